// Round 1
// baseline (236.211 us; speedup 1.0000x reference)
//
#include <hip/hip_runtime.h>
#include <stdint.h>
#include <stddef.h>

// GRIT attention, MI355X bf16-MFMA implementation.
// Key identity: softmax_j(q.k*scale + pe[j] - pe[i]) == softmax_j(q.k*scale + pe[j])
// -> flash attention with a per-column bias only.

typedef unsigned short u16;
typedef __attribute__((ext_vector_type(8))) short short8;     // MFMA A/B frag (8 bf16)
typedef __attribute__((ext_vector_type(8))) unsigned short us8; // 16B copy
typedef __attribute__((ext_vector_type(4))) unsigned short us4;
typedef __attribute__((ext_vector_type(4))) float floatx4;    // MFMA C/D frag

__device__ __forceinline__ u16 f2b(float f) {
  union { float f; uint32_t u; } v; v.f = f;
  uint32_t u = v.u;
  return (u16)((u + 0x7fffu + ((u >> 16) & 1u)) >> 16);  // RNE
}

// ---------------- prep kernels ----------------

__global__ void k_cast_x(const float* __restrict__ in, u16* __restrict__ out, int n4) {
  int i = blockIdx.x * 256 + threadIdx.x;
  if (i >= n4) return;
  float4 v = ((const float4*)in)[i];
  us4 o; o.x = f2b(v.x); o.y = f2b(v.y); o.z = f2b(v.z); o.w = f2b(v.w);
  ((us4*)out)[i] = o;
}

// out[c][r] = bf16(in[r][c]); grid (C/32, R/32), block 256
__global__ void k_tr_f2b(const float* __restrict__ in, u16* __restrict__ out, int R, int C) {
  __shared__ u16 tile[32][33];
  int tx = threadIdx.x & 31, ty = threadIdx.x >> 5;
  int c0 = blockIdx.x * 32, r0 = blockIdx.y * 32;
#pragma unroll
  for (int i = 0; i < 32; i += 8)
    tile[ty + i][tx] = f2b(in[(size_t)(r0 + ty + i) * C + c0 + tx]);
  __syncthreads();
#pragma unroll
  for (int i = 0; i < 32; i += 8)
    out[(size_t)(c0 + ty + i) * R + r0 + tx] = tile[tx][ty + i];
}

// vt[(h*64+d)][n] = qkv[n][1024 + h*64 + d]; grid (16, 128), block 256
__global__ void k_tr_v(const u16* __restrict__ qkv, u16* __restrict__ vt) {
  __shared__ u16 tile[32][33];
  int tx = threadIdx.x & 31, ty = threadIdx.x >> 5;
  int c0 = blockIdx.x * 32, r0 = blockIdx.y * 32;
#pragma unroll
  for (int i = 0; i < 32; i += 8)
    tile[ty + i][tx] = qkv[(size_t)(r0 + ty + i) * 1536 + 1024 + c0 + tx];
  __syncthreads();
#pragma unroll
  for (int i = 0; i < 32; i += 8)
    vt[(size_t)(c0 + ty + i) * 4096 + r0 + tx] = tile[tx][ty + i];
}

// peT[h][n] = (pe[n]·w_pe[:,h] + b_pe[h]) * log2(e);  grid 128, block 256
__global__ void k_pe(const float* __restrict__ pe, const float* __restrict__ w_pe,
                     const float* __restrict__ b_pe, float* __restrict__ peT) {
  int idx = blockIdx.x * 256 + threadIdx.x;
  int h = idx >> 12, n = idx & 4095;
  float acc = b_pe[h];
#pragma unroll
  for (int d = 0; d < 16; ++d) acc = fmaf(pe[n * 16 + d], w_pe[d * 8 + h], acc);
  peT[h * 4096 + n] = acc * 1.4426950408889634f;
}

// ---------------- GEMMs: C = A @ B (+bias), Bt given as [N][K] ----------------
// 128x128 tile, BK=32, 4 waves in 2x2, each wave 64x64 = 4x4 MFMA blocks.
// LDS rows padded to 40 u16 (80B) -> 2-way-only bank aliasing (free).

#define LDT 40

__global__ __launch_bounds__(256) void k_gemm_qkv(const u16* __restrict__ A,
                                                  const u16* __restrict__ Bt,
                                                  const float* __restrict__ bias,
                                                  u16* __restrict__ Cout) {
  __shared__ u16 As[128 * LDT];
  __shared__ u16 Bs[128 * LDT];
  const int tid = threadIdx.x;
  const int lane = tid & 63, wave = tid >> 6;
  const int colx = lane & 15, quad = lane >> 4;
  const int m0 = blockIdx.y * 128, n0 = blockIdx.x * 128;
  const int wr = (wave >> 1) * 64, wc = (wave & 1) * 64;
  const floatx4 fz = {0.f, 0.f, 0.f, 0.f};
  floatx4 acc[4][4];
#pragma unroll
  for (int i = 0; i < 4; ++i)
#pragma unroll
    for (int j = 0; j < 4; ++j) acc[i][j] = fz;

  for (int k0 = 0; k0 < 512; k0 += 32) {
    __syncthreads();
#pragma unroll
    for (int r = 0; r < 2; ++r) {
      int idx = r * 256 + tid;
      int row = idx >> 2, ch = idx & 3;
      *(us8*)&As[row * LDT + ch * 8] =
          *(const us8*)&A[(size_t)(m0 + row) * 512 + k0 + ch * 8];
      *(us8*)&Bs[row * LDT + ch * 8] =
          *(const us8*)&Bt[(size_t)(n0 + row) * 512 + k0 + ch * 8];
    }
    __syncthreads();
    short8 af[4], bf[4];
#pragma unroll
    for (int i = 0; i < 4; ++i)
      af[i] = *(const short8*)&As[(wr + i * 16 + colx) * LDT + quad * 8];
#pragma unroll
    for (int j = 0; j < 4; ++j)
      bf[j] = *(const short8*)&Bs[(wc + j * 16 + colx) * LDT + quad * 8];
#pragma unroll
    for (int i = 0; i < 4; ++i)
#pragma unroll
      for (int j = 0; j < 4; ++j)
        acc[i][j] = __builtin_amdgcn_mfma_f32_16x16x32_bf16(af[i], bf[j], acc[i][j], 0, 0, 0);
  }
#pragma unroll
  for (int j = 0; j < 4; ++j) {
    int c = n0 + wc + j * 16 + colx;
    float bq = bias[c];
#pragma unroll
    for (int i = 0; i < 4; ++i)
#pragma unroll
      for (int r = 0; r < 4; ++r) {
        int row = m0 + wr + i * 16 + quad * 4 + r;
        Cout[(size_t)row * 1536 + c] = f2b(acc[i][j][r] + bq);
      }
  }
}

__global__ __launch_bounds__(256) void k_gemm_out(const u16* __restrict__ A,
                                                  const u16* __restrict__ Bt,
                                                  const float* __restrict__ bias,
                                                  float* __restrict__ Cout) {
  __shared__ u16 As[128 * LDT];
  __shared__ u16 Bs[128 * LDT];
  const int tid = threadIdx.x;
  const int lane = tid & 63, wave = tid >> 6;
  const int colx = lane & 15, quad = lane >> 4;
  const int m0 = blockIdx.y * 128, n0 = blockIdx.x * 128;
  const int wr = (wave >> 1) * 64, wc = (wave & 1) * 64;
  const floatx4 fz = {0.f, 0.f, 0.f, 0.f};
  floatx4 acc[4][4];
#pragma unroll
  for (int i = 0; i < 4; ++i)
#pragma unroll
    for (int j = 0; j < 4; ++j) acc[i][j] = fz;

  for (int k0 = 0; k0 < 512; k0 += 32) {
    __syncthreads();
#pragma unroll
    for (int r = 0; r < 2; ++r) {
      int idx = r * 256 + tid;
      int row = idx >> 2, ch = idx & 3;
      *(us8*)&As[row * LDT + ch * 8] =
          *(const us8*)&A[(size_t)(m0 + row) * 512 + k0 + ch * 8];
      *(us8*)&Bs[row * LDT + ch * 8] =
          *(const us8*)&Bt[(size_t)(n0 + row) * 512 + k0 + ch * 8];
    }
    __syncthreads();
    short8 af[4], bf[4];
#pragma unroll
    for (int i = 0; i < 4; ++i)
      af[i] = *(const short8*)&As[(wr + i * 16 + colx) * LDT + quad * 8];
#pragma unroll
    for (int j = 0; j < 4; ++j)
      bf[j] = *(const short8*)&Bs[(wc + j * 16 + colx) * LDT + quad * 8];
#pragma unroll
    for (int i = 0; i < 4; ++i)
#pragma unroll
      for (int j = 0; j < 4; ++j)
        acc[i][j] = __builtin_amdgcn_mfma_f32_16x16x32_bf16(af[i], bf[j], acc[i][j], 0, 0, 0);
  }
#pragma unroll
  for (int j = 0; j < 4; ++j) {
    int c = n0 + wc + j * 16 + colx;
    float bq = bias[c];
#pragma unroll
    for (int i = 0; i < 4; ++i)
#pragma unroll
      for (int r = 0; r < 4; ++r) {
        int row = m0 + wr + i * 16 + quad * 4 + r;
        Cout[(size_t)row * 512 + c] = acc[i][j][r] + bq;
      }
  }
}

// ---------------- flash attention ----------------
// Q tile 64 rows, KV tile 128, 4 waves (16 Q-rows each).
// Softmax in exp2 domain; scale*log2e folded into score FMA; peT pre-scaled by log2e.

__global__ __launch_bounds__(256) void k_flash(const u16* __restrict__ qkv,
                                               const u16* __restrict__ vt,
                                               const float* __restrict__ peT,
                                               u16* __restrict__ ao) {
  __shared__ u16 Qs[64 * 72];
  __shared__ u16 Ks[128 * 72];
  __shared__ u16 Vts[64 * 136];
  __shared__ u16 Ps[64 * 136];
  __shared__ float pes[128];

  const int tid = threadIdx.x;
  const int lane = tid & 63, wave = tid >> 6;
  const int colx = lane & 15, quad = lane >> 4;
  const int q0 = blockIdx.x * 64;
  const int h = blockIdx.y;
  const int wr = wave * 16;
  const float sscale = 0.125f * 1.4426950408889634f;  // hd^-0.5 * log2(e)
  const floatx4 fz = {0.f, 0.f, 0.f, 0.f};

  // stage Q (raw bf16 from qkv cols [h*64, h*64+64))
#pragma unroll
  for (int r = 0; r < 2; ++r) {
    int idx = r * 256 + tid;
    int row = idx >> 3, ch = idx & 7;
    *(us8*)&Qs[row * 72 + ch * 8] =
        *(const us8*)&qkv[(size_t)(q0 + row) * 1536 + h * 64 + ch * 8];
  }

  float m_run[4], l_run[4];
#pragma unroll
  for (int r = 0; r < 4; ++r) { m_run[r] = -1e30f; l_run[r] = 0.0f; }
  floatx4 oacc[4];
#pragma unroll
  for (int cb = 0; cb < 4; ++cb) oacc[cb] = fz;

  for (int j0 = 0; j0 < 4096; j0 += 128) {
    __syncthreads();
    // stage K tile [128][64] (cols [512+h*64, ...))
#pragma unroll
    for (int r = 0; r < 4; ++r) {
      int idx = r * 256 + tid;
      int row = idx >> 3, ch = idx & 7;
      *(us8*)&Ks[row * 72 + ch * 8] =
          *(const us8*)&qkv[(size_t)(j0 + row) * 1536 + 512 + h * 64 + ch * 8];
    }
    // stage V^T tile [64][128]
#pragma unroll
    for (int r = 0; r < 4; ++r) {
      int idx = r * 256 + tid;
      int row = idx >> 4, ch = idx & 15;
      *(us8*)&Vts[row * 136 + ch * 8] =
          *(const us8*)&vt[(size_t)(h * 64 + row) * 4096 + j0 + ch * 8];
    }
    if (tid < 128) pes[tid] = peT[h * 4096 + j0 + tid];
    __syncthreads();

    // S = Q K^T : 1x8 blocks of 16x16 per wave, K=64 in 2 MFMA steps
    floatx4 sacc[8];
#pragma unroll
    for (int j = 0; j < 8; ++j) sacc[j] = fz;
#pragma unroll
    for (int kk = 0; kk < 2; ++kk) {
      short8 af = *(const short8*)&Qs[(wr + colx) * 72 + kk * 32 + quad * 8];
#pragma unroll
      for (int j = 0; j < 8; ++j) {
        short8 bfr = *(const short8*)&Ks[(j * 16 + colx) * 72 + kk * 32 + quad * 8];
        sacc[j] = __builtin_amdgcn_mfma_f32_16x16x32_bf16(af, bfr, sacc[j], 0, 0, 0);
      }
    }

    // scores (exp2 domain) + column bias, tile row-max
    float tmax[4] = {-1e30f, -1e30f, -1e30f, -1e30f};
#pragma unroll
    for (int j = 0; j < 8; ++j) {
      float pj = pes[j * 16 + colx];
#pragma unroll
      for (int r = 0; r < 4; ++r) {
        float s = fmaf(sacc[j][r], sscale, pj);
        sacc[j][r] = s;
        tmax[r] = fmaxf(tmax[r], s);
      }
    }
#pragma unroll
    for (int r = 0; r < 4; ++r) {
#pragma unroll
      for (int off = 1; off < 16; off <<= 1)
        tmax[r] = fmaxf(tmax[r], __shfl_xor(tmax[r], off, 16));
    }
    float alpha[4], rsum[4];
#pragma unroll
    for (int r = 0; r < 4; ++r) {
      float mn = fmaxf(m_run[r], tmax[r]);
      alpha[r] = exp2f(m_run[r] - mn);
      m_run[r] = mn;
      rsum[r] = 0.0f;
    }
#pragma unroll
    for (int j = 0; j < 8; ++j) {
#pragma unroll
      for (int r = 0; r < 4; ++r) {
        float p = exp2f(sacc[j][r] - m_run[r]);
        sacc[j][r] = p;
        rsum[r] += p;
      }
    }
#pragma unroll
    for (int r = 0; r < 4; ++r) {
#pragma unroll
      for (int off = 1; off < 16; off <<= 1)
        rsum[r] += __shfl_xor(rsum[r], off, 16);
      l_run[r] = l_run[r] * alpha[r] + rsum[r];
    }
#pragma unroll
    for (int cb = 0; cb < 4; ++cb)
#pragma unroll
      for (int r = 0; r < 4; ++r) oacc[cb][r] *= alpha[r];

    // P: C-layout -> LDS -> A-layout (wave-local rows; no barrier needed)
#pragma unroll
    for (int j = 0; j < 8; ++j)
#pragma unroll
      for (int r = 0; r < 4; ++r)
        Ps[(wr + quad * 4 + r) * 136 + j * 16 + colx] = f2b(sacc[j][r]);
    __asm__ volatile("s_waitcnt lgkmcnt(0)" ::: "memory");

    // O += P @ V : 1x4 blocks, K=128 in 4 MFMA steps
#pragma unroll
    for (int kk = 0; kk < 4; ++kk) {
      short8 af = *(const short8*)&Ps[(wr + colx) * 136 + kk * 32 + quad * 8];
#pragma unroll
      for (int cb = 0; cb < 4; ++cb) {
        short8 bfr = *(const short8*)&Vts[(cb * 16 + colx) * 136 + kk * 32 + quad * 8];
        oacc[cb] = __builtin_amdgcn_mfma_f32_16x16x32_bf16(af, bfr, oacc[cb], 0, 0, 0);
      }
    }
  }

  float invl[4];
#pragma unroll
  for (int r = 0; r < 4; ++r) invl[r] = 1.0f / l_run[r];
#pragma unroll
  for (int cb = 0; cb < 4; ++cb)
#pragma unroll
    for (int r = 0; r < 4; ++r) {
      int row = q0 + wr + quad * 4 + r;
      int c = h * 64 + cb * 16 + colx;
      ao[(size_t)row * 512 + c] = f2b(oacc[cb][r] * invl[r]);
    }
}

// ---------------- launch ----------------

extern "C" void kernel_launch(void* const* d_in, const int* in_sizes, int n_in,
                              void* d_out, int out_size, void* d_ws, size_t ws_size,
                              hipStream_t stream) {
  const float* x     = (const float*)d_in[0];
  const float* pe    = (const float*)d_in[1];
  const float* w_qkv = (const float*)d_in[2];
  const float* b_qkv = (const float*)d_in[3];
  const float* w_pe  = (const float*)d_in[4];
  const float* b_pe  = (const float*)d_in[5];
  const float* w_out = (const float*)d_in[6];
  const float* b_out = (const float*)d_in[7];
  float* out = (float*)d_out;

  // workspace layout (u16 elements)
  u16* xb    = (u16*)d_ws;              // 4096*512
  u16* wqkvT = xb    + 2097152;         // 1536*512
  u16* woutT = wqkvT + 786432;          // 512*512
  u16* qkv   = woutT + 262144;          // 4096*1536
  u16* vt    = qkv   + 6291456;         // 512*4096
  u16* ao    = vt    + 2097152;         // 4096*512
  float* peT = (float*)(ao + 2097152);  // 8*4096 floats

  k_cast_x<<<2048, 256, 0, stream>>>(x, xb, 524288);
  k_tr_f2b<<<dim3(48, 16), 256, 0, stream>>>(w_qkv, wqkvT, 512, 1536);
  k_tr_f2b<<<dim3(16, 16), 256, 0, stream>>>(w_out, woutT, 512, 512);
  k_pe<<<128, 256, 0, stream>>>(pe, w_pe, b_pe, peT);
  k_gemm_qkv<<<dim3(12, 32), 256, 0, stream>>>(xb, wqkvT, b_qkv, qkv);
  k_tr_v<<<dim3(16, 128), 256, 0, stream>>>(qkv, vt);
  k_flash<<<dim3(64, 8), 256, 0, stream>>>(qkv, vt, peT, ao);
  k_gemm_out<<<dim3(4, 32), 256, 0, stream>>>(ao, woutT, b_out, out);
}

// Round 3
// 200.211 us; speedup vs baseline: 1.1798x; 1.1798x over previous
//
#include <hip/hip_runtime.h>
#include <stdint.h>
#include <stddef.h>

// GRIT attention, MI355X bf16-MFMA implementation, round 3 (= round 2 + ldc fix).
// softmax_j(q.k*scale + pe[j] - pe[i]) == softmax_j(q.k*scale + pe[j])
// -> flash attention with per-column bias only.
// R2: S^T = K*Q^T so P^T lands in C-layout == A-layout of 16x16x16 MFMA
//     -> no LDS round-trip for P (R1: 9.96M bank-conflict cycles, 17.4KB LDS).

typedef unsigned short u16;
typedef __attribute__((ext_vector_type(8))) short short8;      // K=32 MFMA A/B frag
typedef __attribute__((ext_vector_type(4))) short shortx4;     // K=16 MFMA A/B frag
typedef __attribute__((ext_vector_type(8))) unsigned short us8;
typedef __attribute__((ext_vector_type(4))) unsigned short us4;
typedef __attribute__((ext_vector_type(4))) float floatx4;

__device__ __forceinline__ u16 f2b(float f) {
  union { float f; uint32_t u; } v; v.f = f;
  uint32_t u = v.u;
  return (u16)((u + 0x7fffu + ((u >> 16) & 1u)) >> 16);  // RNE
}

#if __has_builtin(__builtin_amdgcn_exp2f)
__device__ __forceinline__ float fexp2(float x) { return __builtin_amdgcn_exp2f(x); }
#else
__device__ __forceinline__ float fexp2(float x) { return exp2f(x); }
#endif

#if __has_builtin(__builtin_amdgcn_mfma_f32_16x16x16_bf16)
#define MFMA16(a, b, c) __builtin_amdgcn_mfma_f32_16x16x16_bf16(a, b, c, 0, 0, 0)
#elif __has_builtin(__builtin_amdgcn_mfma_f32_16x16x16bf16_1k)
#define MFMA16(a, b, c) __builtin_amdgcn_mfma_f32_16x16x16bf16_1k(a, b, c, 0, 0, 0)
#else
static __device__ __forceinline__ floatx4 mfma16_asm(shortx4 a, shortx4 b, floatx4 c) {
  asm volatile("v_mfma_f32_16x16x16_bf16 %0, %1, %2, %0\n\ts_nop 7\n\ts_nop 3"
               : "+v"(c) : "v"(a), "v"(b));
  return c;
}
#define MFMA16(a, b, c) mfma16_asm(a, b, c)
#endif

// ---------------- prep kernels ----------------

__global__ void k_cast_x(const float* __restrict__ in, u16* __restrict__ out, int n4) {
  int i = blockIdx.x * 256 + threadIdx.x;
  if (i >= n4) return;
  float4 v = ((const float4*)in)[i];
  us4 o; o.x = f2b(v.x); o.y = f2b(v.y); o.z = f2b(v.z); o.w = f2b(v.w);
  ((us4*)out)[i] = o;
}

// out[c][r] = bf16(in[r][c]); grid (C/32, R/32), block 256
__global__ void k_tr_f2b(const float* __restrict__ in, u16* __restrict__ out, int R, int C) {
  __shared__ u16 tile[32][33];
  int tx = threadIdx.x & 31, ty = threadIdx.x >> 5;
  int c0 = blockIdx.x * 32, r0 = blockIdx.y * 32;
#pragma unroll
  for (int i = 0; i < 32; i += 8)
    tile[ty + i][tx] = f2b(in[(size_t)(r0 + ty + i) * C + c0 + tx]);
  __syncthreads();
#pragma unroll
  for (int i = 0; i < 32; i += 8)
    out[(size_t)(c0 + ty + i) * R + r0 + tx] = tile[tx][ty + i];
}

// vt[(h*64+d)][n] = qkv[n][1024 + h*64 + d]; grid (16, 128), block 256
__global__ void k_tr_v(const u16* __restrict__ qkv, u16* __restrict__ vt) {
  __shared__ u16 tile[32][33];
  int tx = threadIdx.x & 31, ty = threadIdx.x >> 5;
  int c0 = blockIdx.x * 32, r0 = blockIdx.y * 32;
#pragma unroll
  for (int i = 0; i < 32; i += 8)
    tile[ty + i][tx] = qkv[(size_t)(r0 + ty + i) * 1536 + 1024 + c0 + tx];
  __syncthreads();
#pragma unroll
  for (int i = 0; i < 32; i += 8)
    vt[(size_t)(c0 + ty + i) * 4096 + r0 + tx] = tile[tx][ty + i];
}

// peT[h][n] = (pe[n]·w_pe[:,h] + b_pe[h]) * log2(e);  grid 128, block 256
__global__ void k_pe(const float* __restrict__ pe, const float* __restrict__ w_pe,
                     const float* __restrict__ b_pe, float* __restrict__ peT) {
  int idx = blockIdx.x * 256 + threadIdx.x;
  int h = idx >> 12, n = idx & 4095;
  float acc = b_pe[h];
#pragma unroll
  for (int d = 0; d < 16; ++d) acc = fmaf(pe[n * 16 + d], w_pe[d * 8 + h], acc);
  peT[h * 4096 + n] = acc * 1.4426950408889634f;
}

// ---------------- GEMM template: C = A @ B (+bias), Bt given [N][K], K=512 ----
// 4 waves in 2x2; LDS rows padded to 40 u16 -> 2-way-only bank aliasing (free).

template <int TM, int TN, bool BOUT>
__global__ __launch_bounds__(256) void k_gemm(const u16* __restrict__ A,
                                              const u16* __restrict__ Bt,
                                              const float* __restrict__ bias,
                                              void* __restrict__ Cp, int ldc) {
  constexpr int AI = TM / 32, AJ = TN / 32;   // acc blocks per wave
  constexpr int CA = TM / 64, CB = TN / 64;   // staging chunks per thread
  __shared__ u16 As[TM * 40];
  __shared__ u16 Bs[TN * 40];
  const int tid = threadIdx.x;
  const int lane = tid & 63, wave = tid >> 6;
  const int colx = lane & 15, quad = lane >> 4;
  const int m0 = blockIdx.y * TM, n0 = blockIdx.x * TN;
  const int wr = (wave >> 1) * (TM / 2), wc = (wave & 1) * (TN / 2);
  const floatx4 fz = {0.f, 0.f, 0.f, 0.f};
  floatx4 acc[AI][AJ];
#pragma unroll
  for (int i = 0; i < AI; ++i)
#pragma unroll
    for (int j = 0; j < AJ; ++j) acc[i][j] = fz;

  for (int k0 = 0; k0 < 512; k0 += 32) {
    __syncthreads();
#pragma unroll
    for (int r = 0; r < CA; ++r) {
      int idx = r * 256 + tid;
      int row = idx >> 2, ch = idx & 3;
      *(us8*)&As[row * 40 + ch * 8] =
          *(const us8*)&A[(size_t)(m0 + row) * 512 + k0 + ch * 8];
    }
#pragma unroll
    for (int r = 0; r < CB; ++r) {
      int idx = r * 256 + tid;
      int row = idx >> 2, ch = idx & 3;
      *(us8*)&Bs[row * 40 + ch * 8] =
          *(const us8*)&Bt[(size_t)(n0 + row) * 512 + k0 + ch * 8];
    }
    __syncthreads();
    short8 af[AI], bf[AJ];
#pragma unroll
    for (int i = 0; i < AI; ++i)
      af[i] = *(const short8*)&As[(wr + i * 16 + colx) * 40 + quad * 8];
#pragma unroll
    for (int j = 0; j < AJ; ++j)
      bf[j] = *(const short8*)&Bs[(wc + j * 16 + colx) * 40 + quad * 8];
#pragma unroll
    for (int i = 0; i < AI; ++i)
#pragma unroll
      for (int j = 0; j < AJ; ++j)
        acc[i][j] = __builtin_amdgcn_mfma_f32_16x16x32_bf16(af[i], bf[j], acc[i][j], 0, 0, 0);
  }
#pragma unroll
  for (int j = 0; j < AJ; ++j) {
    int c = n0 + wc + j * 16 + colx;
    float bq = bias[c];
#pragma unroll
    for (int i = 0; i < AI; ++i)
#pragma unroll
      for (int r = 0; r < 4; ++r) {
        int row = m0 + wr + i * 16 + quad * 4 + r;
        float v = acc[i][j][r] + bq;
        if (BOUT)
          ((u16*)Cp)[(size_t)row * ldc + c] = f2b(v);
        else
          ((float*)Cp)[(size_t)row * ldc + c] = v;
      }
  }
}

// ---------------- flash attention ----------------
// Q tile 64 rows, KV tile 128, 4 waves (16 Q-rows each).
// S^T = K Q^T (C-layout: lane holds S^T[j=blk*16+quad*4+r][i=colx]) -> P^T in
// registers is already the A-operand layout of 16x16x16 MFMA for O = P V.
// Softmax in exp2 domain; scale*log2e folded; peT pre-scaled by log2e.

__global__ __launch_bounds__(256) void k_flash(const u16* __restrict__ qkv,
                                               const u16* __restrict__ vt,
                                               const float* __restrict__ peT,
                                               u16* __restrict__ ao) {
  __shared__ u16 Qs[64 * 72];
  __shared__ u16 Ks[128 * 72];
  __shared__ u16 Vts[64 * 136];
  __shared__ __align__(16) float pes[128];

  const int tid = threadIdx.x;
  const int lane = tid & 63, wave = tid >> 6;
  const int colx = lane & 15, quad = lane >> 4;
  const int q0 = blockIdx.x * 64;
  const int h = blockIdx.y;
  const float sscale = 0.125f * 1.4426950408889634f;  // hd^-0.5 * log2(e)
  const floatx4 fz = {0.f, 0.f, 0.f, 0.f};

  // stage Q (bf16 from qkv cols [h*64, h*64+64))
#pragma unroll
  for (int r = 0; r < 2; ++r) {
    int idx = r * 256 + tid;
    int row = idx >> 3, ch = idx & 7;
    *(us8*)&Qs[row * 72 + ch * 8] =
        *(const us8*)&qkv[(size_t)(q0 + row) * 1536 + h * 64 + ch * 8];
  }

  float m_run = -1e30f, l_run = 0.0f;
  floatx4 oacc[4];
#pragma unroll
  for (int cb = 0; cb < 4; ++cb) oacc[cb] = fz;

  for (int j0 = 0; j0 < 4096; j0 += 128) {
    __syncthreads();
#pragma unroll
    for (int r = 0; r < 4; ++r) {   // K tile [128][64]
      int idx = r * 256 + tid;
      int row = idx >> 3, ch = idx & 7;
      *(us8*)&Ks[row * 72 + ch * 8] =
          *(const us8*)&qkv[(size_t)(j0 + row) * 1536 + 512 + h * 64 + ch * 8];
    }
#pragma unroll
    for (int r = 0; r < 4; ++r) {   // V^T tile [64][128]
      int idx = r * 256 + tid;
      int row = idx >> 4, ch = idx & 15;
      *(us8*)&Vts[row * 136 + ch * 8] =
          *(const us8*)&vt[(size_t)(h * 64 + row) * 4096 + j0 + ch * 8];
    }
    if (tid < 128) pes[tid] = peT[h * 4096 + j0 + tid];
    __syncthreads();

    // S^T = K Q^T : 8 j-blocks per wave, K=64 in 2 MFMA steps
    floatx4 sacc[8];
#pragma unroll
    for (int b = 0; b < 8; ++b) sacc[b] = fz;
#pragma unroll
    for (int kk = 0; kk < 2; ++kk) {
      short8 qf = *(const short8*)&Qs[(wave * 16 + colx) * 72 + kk * 32 + quad * 8];
#pragma unroll
      for (int b = 0; b < 8; ++b) {
        short8 kf = *(const short8*)&Ks[(b * 16 + colx) * 72 + kk * 32 + quad * 8];
        sacc[b] = __builtin_amdgcn_mfma_f32_16x16x32_bf16(kf, qf, sacc[b], 0, 0, 0);
      }
    }

    // bias (per j = row of S^T) + tile max (per i = colx)
    float tmax = -1e30f;
#pragma unroll
    for (int b = 0; b < 8; ++b) {
      floatx4 pev = *(const floatx4*)&pes[b * 16 + quad * 4];
#pragma unroll
      for (int r = 0; r < 4; ++r) {
        float s = fmaf(sacc[b][r], sscale, pev[r]);
        sacc[b][r] = s;
        tmax = fmaxf(tmax, s);
      }
    }
    tmax = fmaxf(tmax, __shfl_xor(tmax, 16));
    tmax = fmaxf(tmax, __shfl_xor(tmax, 32));
    float mn = fmaxf(m_run, tmax);
    float alpha = fexp2(m_run - mn);
    m_run = mn;

    float rsum = 0.0f;
    shortx4 paf[8];
#pragma unroll
    for (int b = 0; b < 8; ++b) {
#pragma unroll
      for (int r = 0; r < 4; ++r) {
        float p = fexp2(sacc[b][r] - mn);
        rsum += p;
        paf[b][r] = (short)f2b(p);
      }
    }
    rsum += __shfl_xor(rsum, 16);
    rsum += __shfl_xor(rsum, 32);
    l_run = l_run * alpha + rsum;

    // redistribute alpha from i=colx indexing to O's i=quad*4+r indexing
    float alo[4];
#pragma unroll
    for (int r = 0; r < 4; ++r) alo[r] = __shfl(alpha, quad * 4 + r, 16);
#pragma unroll
    for (int cb = 0; cb < 4; ++cb)
#pragma unroll
      for (int r = 0; r < 4; ++r) oacc[cb][r] *= alo[r];

    // O += P V : K=16 MFMA, A-frag = paf (registers), B-frag from Vts
#pragma unroll
    for (int s = 0; s < 8; ++s) {
#pragma unroll
      for (int cb = 0; cb < 4; ++cb) {
        shortx4 vf = *(const shortx4*)&Vts[(cb * 16 + colx) * 136 + s * 16 + quad * 4];
        oacc[cb] = MFMA16(paf[s], vf, oacc[cb]);
      }
    }
  }

  float inv = 1.0f / l_run;
  float ivo[4];
#pragma unroll
  for (int r = 0; r < 4; ++r) ivo[r] = __shfl(inv, quad * 4 + r, 16);
#pragma unroll
  for (int cb = 0; cb < 4; ++cb)
#pragma unroll
    for (int r = 0; r < 4; ++r) {
      int row = q0 + wave * 16 + quad * 4 + r;
      int c = h * 64 + cb * 16 + colx;
      ao[(size_t)row * 512 + c] = f2b(oacc[cb][r] * ivo[r]);
    }
}

// ---------------- launch ----------------

extern "C" void kernel_launch(void* const* d_in, const int* in_sizes, int n_in,
                              void* d_out, int out_size, void* d_ws, size_t ws_size,
                              hipStream_t stream) {
  const float* x     = (const float*)d_in[0];
  const float* pe    = (const float*)d_in[1];
  const float* w_qkv = (const float*)d_in[2];
  const float* b_qkv = (const float*)d_in[3];
  const float* w_pe  = (const float*)d_in[4];
  const float* b_pe  = (const float*)d_in[5];
  const float* w_out = (const float*)d_in[6];
  const float* b_out = (const float*)d_in[7];
  float* out = (float*)d_out;

  // workspace layout (u16 elements)
  u16* xb    = (u16*)d_ws;              // 4096*512
  u16* wqkvT = xb    + 2097152;         // 1536*512
  u16* woutT = wqkvT + 786432;          // 512*512
  u16* qkv   = woutT + 262144;          // 4096*1536
  u16* vt    = qkv   + 6291456;         // 512*4096
  u16* ao    = vt    + 2097152;         // 4096*512
  float* peT = (float*)(ao + 2097152);  // 8*4096 floats

  k_cast_x<<<2048, 256, 0, stream>>>(x, xb, 524288);
  k_tr_f2b<<<dim3(48, 16), 256, 0, stream>>>(w_qkv, wqkvT, 512, 1536);
  k_tr_f2b<<<dim3(16, 16), 256, 0, stream>>>(w_out, woutT, 512, 512);
  k_pe<<<128, 256, 0, stream>>>(pe, w_pe, b_pe, peT);
  k_gemm<64, 128, true><<<dim3(12, 64), 256, 0, stream>>>(xb, wqkvT, b_qkv, qkv, 1536);
  k_tr_v<<<dim3(16, 128), 256, 0, stream>>>(qkv, vt);
  k_flash<<<dim3(64, 8), 256, 0, stream>>>(qkv, vt, peT, ao);
  k_gemm<64, 64, false><<<dim3(8, 64), 256, 0, stream>>>(ao, woutT, b_out, out, 512);
}

// Round 4
// 185.571 us; speedup vs baseline: 1.2729x; 1.0789x over previous
//
#include <hip/hip_runtime.h>
#include <stdint.h>
#include <stddef.h>

// GRIT attention, MI355X bf16-MFMA implementation, round 4.
// softmax_j(q.k*scale + pe[j] - pe[i]) == softmax_j(q.k*scale + pe[j])
// -> flash attention with per-column bias only.
// R4: fixed-max softmax (M=16 in exp2 domain, safe: |scores*log2e| <~ 13) makes
//     the KV loop LINEAR -> no online max/alpha/shuffles; l via ones-column MFMA.
//     8 waves = 2(q-half) x 4(kv-quarter); Q-frags in registers; Vts stride 132
//     (264B = 2 banks) fixes the even-bank-only b64 pattern of stride 136.

typedef unsigned short u16;
typedef __attribute__((ext_vector_type(8))) short short8;      // K=32 MFMA A/B frag
typedef __attribute__((ext_vector_type(4))) short shortx4;     // K=16 MFMA A/B frag
typedef __attribute__((ext_vector_type(8))) unsigned short us8;
typedef __attribute__((ext_vector_type(4))) unsigned short us4;
typedef __attribute__((ext_vector_type(4))) float floatx4;

__device__ __forceinline__ u16 f2b(float f) {
  union { float f; uint32_t u; } v; v.f = f;
  uint32_t u = v.u;
  return (u16)((u + 0x7fffu + ((u >> 16) & 1u)) >> 16);  // RNE
}

#if __has_builtin(__builtin_amdgcn_exp2f)
__device__ __forceinline__ float fexp2(float x) { return __builtin_amdgcn_exp2f(x); }
#else
__device__ __forceinline__ float fexp2(float x) { return exp2f(x); }
#endif

#if __has_builtin(__builtin_amdgcn_mfma_f32_16x16x16_bf16)
#define MFMA16(a, b, c) __builtin_amdgcn_mfma_f32_16x16x16_bf16(a, b, c, 0, 0, 0)
#elif __has_builtin(__builtin_amdgcn_mfma_f32_16x16x16bf16_1k)
#define MFMA16(a, b, c) __builtin_amdgcn_mfma_f32_16x16x16bf16_1k(a, b, c, 0, 0, 0)
#else
static __device__ __forceinline__ floatx4 mfma16_asm(shortx4 a, shortx4 b, floatx4 c) {
  asm volatile("v_mfma_f32_16x16x16_bf16 %0, %1, %2, %0\n\ts_nop 7\n\ts_nop 3"
               : "+v"(c) : "v"(a), "v"(b));
  return c;
}
#define MFMA16(a, b, c) mfma16_asm(a, b, c)
#endif

// ---------------- prep kernels ----------------

__global__ void k_cast_x(const float* __restrict__ in, u16* __restrict__ out, int n4) {
  int i = blockIdx.x * 256 + threadIdx.x;
  if (i >= n4) return;
  float4 v = ((const float4*)in)[i];
  us4 o; o.x = f2b(v.x); o.y = f2b(v.y); o.z = f2b(v.z); o.w = f2b(v.w);
  ((us4*)out)[i] = o;
}

// out[c][r] = bf16(in[r][c]); grid (C/32, R/32), block 256
__global__ void k_tr_f2b(const float* __restrict__ in, u16* __restrict__ out, int R, int C) {
  __shared__ u16 tile[32][33];
  int tx = threadIdx.x & 31, ty = threadIdx.x >> 5;
  int c0 = blockIdx.x * 32, r0 = blockIdx.y * 32;
#pragma unroll
  for (int i = 0; i < 32; i += 8)
    tile[ty + i][tx] = f2b(in[(size_t)(r0 + ty + i) * C + c0 + tx]);
  __syncthreads();
#pragma unroll
  for (int i = 0; i < 32; i += 8)
    out[(size_t)(c0 + ty + i) * R + r0 + tx] = tile[tx][ty + i];
}

// vt[(h*64+d)][n] = qkv[n][1024 + h*64 + d]; grid (16, 128), block 256
__global__ void k_tr_v(const u16* __restrict__ qkv, u16* __restrict__ vt) {
  __shared__ u16 tile[32][33];
  int tx = threadIdx.x & 31, ty = threadIdx.x >> 5;
  int c0 = blockIdx.x * 32, r0 = blockIdx.y * 32;
#pragma unroll
  for (int i = 0; i < 32; i += 8)
    tile[ty + i][tx] = qkv[(size_t)(r0 + ty + i) * 1536 + 1024 + c0 + tx];
  __syncthreads();
#pragma unroll
  for (int i = 0; i < 32; i += 8)
    vt[(size_t)(c0 + ty + i) * 4096 + r0 + tx] = tile[tx][ty + i];
}

// peT[h][n] = (pe[n]·w_pe[:,h] + b_pe[h]) * log2(e) - 16 (fixed softmax max)
__global__ void k_pe(const float* __restrict__ pe, const float* __restrict__ w_pe,
                     const float* __restrict__ b_pe, float* __restrict__ peT) {
  int idx = blockIdx.x * 256 + threadIdx.x;
  int h = idx >> 12, n = idx & 4095;
  float acc = b_pe[h];
#pragma unroll
  for (int d = 0; d < 16; ++d) acc = fmaf(pe[n * 16 + d], w_pe[d * 8 + h], acc);
  peT[h * 4096 + n] = acc * 1.4426950408889634f - 16.0f;
}

// ---------------- GEMM template: C = A @ B (+bias), Bt given [N][K], K=512 ----

template <int TM, int TN, bool BOUT>
__global__ __launch_bounds__(256) void k_gemm(const u16* __restrict__ A,
                                              const u16* __restrict__ Bt,
                                              const float* __restrict__ bias,
                                              void* __restrict__ Cp, int ldc) {
  constexpr int AI = TM / 32, AJ = TN / 32;
  constexpr int CA = TM / 64, CB = TN / 64;
  __shared__ u16 As[TM * 40];
  __shared__ u16 Bs[TN * 40];
  const int tid = threadIdx.x;
  const int lane = tid & 63, wave = tid >> 6;
  const int colx = lane & 15, quad = lane >> 4;
  const int m0 = blockIdx.y * TM, n0 = blockIdx.x * TN;
  const int wr = (wave >> 1) * (TM / 2), wc = (wave & 1) * (TN / 2);
  const floatx4 fz = {0.f, 0.f, 0.f, 0.f};
  floatx4 acc[AI][AJ];
#pragma unroll
  for (int i = 0; i < AI; ++i)
#pragma unroll
    for (int j = 0; j < AJ; ++j) acc[i][j] = fz;

  for (int k0 = 0; k0 < 512; k0 += 32) {
    __syncthreads();
#pragma unroll
    for (int r = 0; r < CA; ++r) {
      int idx = r * 256 + tid;
      int row = idx >> 2, ch = idx & 3;
      *(us8*)&As[row * 40 + ch * 8] =
          *(const us8*)&A[(size_t)(m0 + row) * 512 + k0 + ch * 8];
    }
#pragma unroll
    for (int r = 0; r < CB; ++r) {
      int idx = r * 256 + tid;
      int row = idx >> 2, ch = idx & 3;
      *(us8*)&Bs[row * 40 + ch * 8] =
          *(const us8*)&Bt[(size_t)(n0 + row) * 512 + k0 + ch * 8];
    }
    __syncthreads();
    short8 af[AI], bf[AJ];
#pragma unroll
    for (int i = 0; i < AI; ++i)
      af[i] = *(const short8*)&As[(wr + i * 16 + colx) * 40 + quad * 8];
#pragma unroll
    for (int j = 0; j < AJ; ++j)
      bf[j] = *(const short8*)&Bs[(wc + j * 16 + colx) * 40 + quad * 8];
#pragma unroll
    for (int i = 0; i < AI; ++i)
#pragma unroll
      for (int j = 0; j < AJ; ++j)
        acc[i][j] = __builtin_amdgcn_mfma_f32_16x16x32_bf16(af[i], bf[j], acc[i][j], 0, 0, 0);
  }
#pragma unroll
  for (int j = 0; j < AJ; ++j) {
    int c = n0 + wc + j * 16 + colx;
    float bq = bias[c];
#pragma unroll
    for (int i = 0; i < AI; ++i)
#pragma unroll
      for (int r = 0; r < 4; ++r) {
        int row = m0 + wr + i * 16 + quad * 4 + r;
        float v = acc[i][j][r] + bq;
        if (BOUT)
          ((u16*)Cp)[(size_t)row * ldc + c] = f2b(v);
        else
          ((float*)Cp)[(size_t)row * ldc + c] = v;
      }
  }
}

// ---------------- flash attention (fixed-max, linear) ----------------
// Q tile 64, KV tile 128, 512 threads = 8 waves: ih = wave&1 (q rows ih*32+32),
// jq = wave>>2... jq = wave>>1 (KV rows jq*32..+32). Q-frags in registers.
// End: O/l reduced across the 4 jq-waves per q-half via LDS tree.

__global__ __launch_bounds__(512, 4) void k_flash(const u16* __restrict__ qkv,
                                                  const u16* __restrict__ vt,
                                                  const float* __restrict__ peT,
                                                  u16* __restrict__ ao) {
  __shared__ __align__(16) u16 smem[17920];  // 35840 B
  u16* Ks = smem;                            // [128][72]
  u16* Vts = smem + 9216;                    // [64][132]
  float* pes = (float*)(smem + 17664);       // [128]
  // epilogue aliases (compute phase over): 4 bufs of 32x65 fp32, order
  // [slot(ih0,k0), slot(ih1,k0), slot(ih0,k1), slot(ih1,k1)]; k0-slots die
  // after S2 -> fin (64x68 u16, 8704B) overlays them at offset 0.
  float* bufs = (float*)smem;
  u16* fin = smem;

  const int tid = threadIdx.x;
  const int lane = tid & 63, wave = tid >> 6;
  const int colx = lane & 15, quad = lane >> 4;
  const int ih = wave & 1, jq = wave >> 1;
  const int q0 = blockIdx.x * 64;
  const int h = blockIdx.y;
  const float sscale = 0.125f * 1.4426950408889634f;
  const floatx4 fz = {0.f, 0.f, 0.f, 0.f};
  const shortx4 onesf = {0x3F80, 0x3F80, 0x3F80, 0x3F80};  // bf16 1.0 x4

  // prologue: stage Q through Ks region, pull loop-invariant Q-frags to regs
  {
    int row = tid >> 3, ch = tid & 7;
    *(us8*)&Ks[row * 72 + ch * 8] =
        *(const us8*)&qkv[(size_t)(q0 + row) * 1536 + h * 64 + ch * 8];
  }
  __syncthreads();
  short8 qf[2][2];
#pragma unroll
  for (int i2 = 0; i2 < 2; ++i2)
#pragma unroll
    for (int kk = 0; kk < 2; ++kk)
      qf[i2][kk] = *(const short8*)&Ks[(ih * 32 + i2 * 16 + colx) * 72 + kk * 32 + quad * 8];

  floatx4 oacc[2][4], lacc[2];
#pragma unroll
  for (int i2 = 0; i2 < 2; ++i2) {
    lacc[i2] = fz;
#pragma unroll
    for (int cb = 0; cb < 4; ++cb) oacc[i2][cb] = fz;
  }

  for (int j0 = 0; j0 < 4096; j0 += 128) {
    __syncthreads();
#pragma unroll
    for (int r = 0; r < 2; ++r) {   // K tile [128][64]
      int idx = r * 512 + tid;
      int row = idx >> 3, ch = idx & 7;
      *(us8*)&Ks[row * 72 + ch * 8] =
          *(const us8*)&qkv[(size_t)(j0 + row) * 1536 + 512 + h * 64 + ch * 8];
    }
#pragma unroll
    for (int r = 0; r < 2; ++r) {   // V^T tile [64][128]
      int idx = r * 512 + tid;
      int row = idx >> 4, ch = idx & 15;
      *(us8*)&Vts[row * 132 + ch * 8] =
          *(const us8*)&vt[(size_t)(h * 64 + row) * 4096 + j0 + ch * 8];
    }
    if (tid < 128) pes[tid] = peT[h * 4096 + j0 + tid];
    __syncthreads();

    short8 kf[2][2];
#pragma unroll
    for (int j2 = 0; j2 < 2; ++j2)
#pragma unroll
      for (int kk = 0; kk < 2; ++kk)
        kf[j2][kk] = *(const short8*)&Ks[(jq * 32 + j2 * 16 + colx) * 72 + kk * 32 + quad * 8];
    shortx4 vf[4][2];
#pragma unroll
    for (int cb = 0; cb < 4; ++cb)
#pragma unroll
      for (int j2 = 0; j2 < 2; ++j2)
        vf[cb][j2] = *(const shortx4*)&Vts[(cb * 16 + colx) * 132 + (jq * 2 + j2) * 16 + quad * 4];

#pragma unroll
    for (int i2 = 0; i2 < 2; ++i2) {
      floatx4 sacc[2] = {fz, fz};
#pragma unroll
      for (int j2 = 0; j2 < 2; ++j2)
#pragma unroll
        for (int kk = 0; kk < 2; ++kk)
          sacc[j2] = __builtin_amdgcn_mfma_f32_16x16x32_bf16(kf[j2][kk], qf[i2][kk], sacc[j2], 0, 0, 0);
#pragma unroll
      for (int j2 = 0; j2 < 2; ++j2) {
        floatx4 pev = *(const floatx4*)&pes[jq * 32 + j2 * 16 + quad * 4];
        shortx4 pf;
#pragma unroll
        for (int r = 0; r < 4; ++r) {
          float p = fexp2(fmaf(sacc[j2][r], sscale, pev[r]));
          pf[r] = (short)f2b(p);
        }
#pragma unroll
        for (int cb = 0; cb < 4; ++cb)
          oacc[i2][cb] = MFMA16(pf, vf[cb][j2], oacc[i2][cb]);
        lacc[i2] = MFMA16(pf, onesf, lacc[i2]);
      }
    }
  }

  // ---- cross-wave reduction over jq (O and l are plain sums: fixed max) ----
  __syncthreads();  // Ks/Vts dead; bufs live
  // slot(ih, k) : k=0 first partial, k=1 second
  float* s0 = bufs + (0 * 2 + ih) * 2080;
  float* s1 = bufs + (1 * 2 + ih) * 2080;
  // S1: jq==2 -> slot k0, jq==3 -> slot k1
  if (jq >= 2) {
    float* b = (jq == 2) ? s0 : s1;
#pragma unroll
    for (int i2 = 0; i2 < 2; ++i2) {
#pragma unroll
      for (int cb = 0; cb < 4; ++cb)
#pragma unroll
        for (int r = 0; r < 4; ++r)
          b[(i2 * 16 + quad * 4 + r) * 65 + cb * 16 + colx] = oacc[i2][cb][r];
      if (colx == 0)
#pragma unroll
        for (int r = 0; r < 4; ++r)
          b[(i2 * 16 + quad * 4 + r) * 65 + 64] = lacc[i2][r];
    }
  }
  __syncthreads();
  // S2: jq==0 += slot k0, jq==1 += slot k1
  if (jq < 2) {
    float* b = (jq == 0) ? s0 : s1;
#pragma unroll
    for (int i2 = 0; i2 < 2; ++i2) {
#pragma unroll
      for (int cb = 0; cb < 4; ++cb)
#pragma unroll
        for (int r = 0; r < 4; ++r)
          oacc[i2][cb][r] += b[(i2 * 16 + quad * 4 + r) * 65 + cb * 16 + colx];
      if (colx == 0)
#pragma unroll
        for (int r = 0; r < 4; ++r)
          lacc[i2][r] += b[(i2 * 16 + quad * 4 + r) * 65 + 64];
    }
  }
  __syncthreads();
  // S3: jq==1 writes its sum into slot k1
  if (jq == 1) {
#pragma unroll
    for (int i2 = 0; i2 < 2; ++i2) {
#pragma unroll
      for (int cb = 0; cb < 4; ++cb)
#pragma unroll
        for (int r = 0; r < 4; ++r)
          s1[(i2 * 16 + quad * 4 + r) * 65 + cb * 16 + colx] = oacc[i2][cb][r];
      if (colx == 0)
#pragma unroll
        for (int r = 0; r < 4; ++r)
          s1[(i2 * 16 + quad * 4 + r) * 65 + 64] = lacc[i2][r];
    }
  }
  __syncthreads();
  // S4: jq==0 adds slot k1 -> full O,l; normalize; bf16 into fin (stride 68)
  if (jq == 0) {
#pragma unroll
    for (int i2 = 0; i2 < 2; ++i2) {
#pragma unroll
      for (int cb = 0; cb < 4; ++cb)
#pragma unroll
        for (int r = 0; r < 4; ++r)
          oacc[i2][cb][r] += s1[(i2 * 16 + quad * 4 + r) * 65 + cb * 16 + colx];
      if (colx == 0)
#pragma unroll
        for (int r = 0; r < 4; ++r)
          lacc[i2][r] += s1[(i2 * 16 + quad * 4 + r) * 65 + 64];
    }
#pragma unroll
    for (int i2 = 0; i2 < 2; ++i2)
#pragma unroll
      for (int r = 0; r < 4; ++r) {
        float inv = 1.0f / __shfl(lacc[i2][r], quad << 4);  // from colx==0 of my quad
#pragma unroll
        for (int cb = 0; cb < 4; ++cb)
          fin[(ih * 32 + i2 * 16 + quad * 4 + r) * 68 + cb * 16 + colx] =
              f2b(oacc[i2][cb][r] * inv);
      }
  }
  __syncthreads();
  // coalesced store of the 64x64 bf16 tile
  {
    int row = tid >> 3, ch = tid & 7;
    *(us8*)&ao[(size_t)(q0 + row) * 512 + h * 64 + ch * 8] =
        *(const us8*)&fin[row * 68 + ch * 8];
  }
}

// ---------------- launch ----------------

extern "C" void kernel_launch(void* const* d_in, const int* in_sizes, int n_in,
                              void* d_out, int out_size, void* d_ws, size_t ws_size,
                              hipStream_t stream) {
  const float* x     = (const float*)d_in[0];
  const float* pe    = (const float*)d_in[1];
  const float* w_qkv = (const float*)d_in[2];
  const float* b_qkv = (const float*)d_in[3];
  const float* w_pe  = (const float*)d_in[4];
  const float* b_pe  = (const float*)d_in[5];
  const float* w_out = (const float*)d_in[6];
  const float* b_out = (const float*)d_in[7];
  float* out = (float*)d_out;

  // workspace layout (u16 elements)
  u16* xb    = (u16*)d_ws;              // 4096*512
  u16* wqkvT = xb    + 2097152;         // 1536*512
  u16* woutT = wqkvT + 786432;          // 512*512
  u16* qkv   = woutT + 262144;          // 4096*1536
  u16* vt    = qkv   + 6291456;         // 512*4096
  u16* ao    = vt    + 2097152;         // 4096*512
  float* peT = (float*)(ao + 2097152);  // 8*4096 floats

  k_cast_x<<<2048, 256, 0, stream>>>(x, xb, 524288);
  k_tr_f2b<<<dim3(48, 16), 256, 0, stream>>>(w_qkv, wqkvT, 512, 1536);
  k_tr_f2b<<<dim3(16, 16), 256, 0, stream>>>(w_out, woutT, 512, 512);
  k_pe<<<128, 256, 0, stream>>>(pe, w_pe, b_pe, peT);
  k_gemm<64, 128, true><<<dim3(12, 64), 256, 0, stream>>>(xb, wqkvT, b_qkv, qkv, 1536);
  k_tr_v<<<dim3(16, 128), 256, 0, stream>>>(qkv, vt);
  k_flash<<<dim3(64, 8), 512, 0, stream>>>(qkv, vt, peT, ao);
  k_gemm<64, 64, false><<<dim3(8, 64), 256, 0, stream>>>(ao, woutT, b_out, out, 512);
}

// Round 5
// 155.804 us; speedup vs baseline: 1.5161x; 1.1910x over previous
//
#include <hip/hip_runtime.h>
#include <stdint.h>
#include <stddef.h>

// GRIT attention, MI355X bf16-MFMA implementation, round 5.
// softmax_j(q.k*scale + pe[j] - pe[i]) == softmax_j(q.k*scale + pe[j])
// -> flash attention with per-column bias only; fixed-max (M=16, exp2 domain)
//    makes the KV loop linear (R4).
// R5: (a) PV uses K=32 MFMA via k-permutation pi(8q+4b+r)=16b+4q+r baked into
//     vt's column order (vt written directly by the QKV GEMM epilogue;
//     k_tr_v eliminated); (b) l via VALU adds in the exp loop (frees 2 MFMAs);
//     (c) v_perm packed bf16 (3 ops/pair vs ~9); (d) prep kernels fused -> 4 launches.

typedef unsigned short u16;
typedef __attribute__((ext_vector_type(8))) short short8;      // K=32 MFMA A/B frag
typedef __attribute__((ext_vector_type(8))) unsigned short us8;
typedef __attribute__((ext_vector_type(4))) unsigned short us4;
typedef __attribute__((ext_vector_type(4))) float floatx4;

__device__ __forceinline__ u16 f2b(float f) {
  union { float f; uint32_t u; } v; v.f = f;
  uint32_t u = v.u;
  return (u16)((u + 0x7fffu + ((u >> 16) & 1u)) >> 16);  // RNE
}

// pack two f32 -> two bf16 (round-half-up) in one dword: add, add, v_perm
__device__ __forceinline__ uint32_t pkbf16(float a, float b) {
  union { float f; uint32_t u; } x, y; x.f = a; y.f = b;
  return __builtin_amdgcn_perm(y.u + 0x8000u, x.u + 0x8000u, 0x07060302u);
}

#if __has_builtin(__builtin_amdgcn_exp2f)
__device__ __forceinline__ float fexp2(float x) { return __builtin_amdgcn_exp2f(x); }
#else
__device__ __forceinline__ float fexp2(float x) { return exp2f(x); }
#endif

// ---------------- fused prep ----------------
// blocks [0,2048): cast x -> bf16
// [2048,2816): transpose w_qkv (512x1536) -> wqkvT
// [2816,3072): transpose w_out (512x512) -> woutT
// [3072,3200): peT[h][n] = (pe[n]._w_pe[:,h]+b_pe[h])*log2e - 16

__device__ __forceinline__ void tr_tile(const float* __restrict__ in,
                                        u16* __restrict__ out, int R, int C,
                                        int bx, int by, u16 (*tile)[33]) {
  int tx = threadIdx.x & 31, ty = threadIdx.x >> 5;
  int c0 = bx * 32, r0 = by * 32;
#pragma unroll
  for (int i = 0; i < 32; i += 8)
    tile[ty + i][tx] = f2b(in[(size_t)(r0 + ty + i) * C + c0 + tx]);
  __syncthreads();
#pragma unroll
  for (int i = 0; i < 32; i += 8)
    out[(size_t)(c0 + ty + i) * R + r0 + tx] = tile[tx][ty + i];
}

__global__ __launch_bounds__(256) void k_prep(
    const float* __restrict__ x, u16* __restrict__ xb,
    const float* __restrict__ w_qkv, u16* __restrict__ wqkvT,
    const float* __restrict__ w_out, u16* __restrict__ woutT,
    const float* __restrict__ pe, const float* __restrict__ w_pe,
    const float* __restrict__ b_pe, float* __restrict__ peT) {
  __shared__ u16 tile[32][33];
  int b = blockIdx.x;
  if (b < 2048) {
    int i = b * 256 + threadIdx.x;
    float4 v = ((const float4*)x)[i];
    uint2 o = make_uint2(pkbf16(v.x, v.y), pkbf16(v.z, v.w));
    ((uint2*)xb)[i] = o;
  } else if (b < 2816) {
    int idx = b - 2048;
    tr_tile(w_qkv, wqkvT, 512, 1536, idx % 48, idx / 48, tile);
  } else if (b < 3072) {
    int idx = b - 2816;
    tr_tile(w_out, woutT, 512, 512, idx % 16, idx / 16, tile);
  } else {
    int idx = (b - 3072) * 256 + threadIdx.x;
    int h = idx >> 12, n = idx & 4095;
    float acc = b_pe[h];
#pragma unroll
    for (int d = 0; d < 16; ++d) acc = fmaf(pe[n * 16 + d], w_pe[d * 8 + h], acc);
    peT[h * 4096 + n] = acc * 1.4426950408889634f - 16.0f;
  }
}

// ---------------- QKV GEMM (64x128 tile) ----------------
// cols < 1024 (Q|K) -> qk[n][1024] bf16, coalesced.
// cols >= 1024 (V)  -> vtp[d][4096] bf16, TRANSPOSED with within-32 column
// permutation pi: value for n = 32a + 16b + 4q + r stored at 32a + 8q + 4b + r
// (so flash's K=32 PV B-frag reads are contiguous b128).

__global__ __launch_bounds__(256) void k_gemm_qkv(const u16* __restrict__ A,
                                                  const u16* __restrict__ Bt,
                                                  const float* __restrict__ bias,
                                                  u16* __restrict__ qk,
                                                  u16* __restrict__ vtp) {
  __shared__ u16 As[64 * 40];
  __shared__ u16 Bs[128 * 40];
  const int tid = threadIdx.x;
  const int lane = tid & 63, wave = tid >> 6;
  const int colx = lane & 15, quad = lane >> 4;
  const int m0 = blockIdx.y * 64, n0 = blockIdx.x * 128;
  const int wr = (wave >> 1) * 32, wc = (wave & 1) * 64;
  const floatx4 fz = {0.f, 0.f, 0.f, 0.f};
  floatx4 acc[2][4];
#pragma unroll
  for (int i = 0; i < 2; ++i)
#pragma unroll
    for (int j = 0; j < 4; ++j) acc[i][j] = fz;

  for (int k0 = 0; k0 < 512; k0 += 32) {
    __syncthreads();
    {
      int row = tid >> 2, ch = tid & 3;
      *(us8*)&As[row * 40 + ch * 8] =
          *(const us8*)&A[(size_t)(m0 + row) * 512 + k0 + ch * 8];
    }
#pragma unroll
    for (int r = 0; r < 2; ++r) {
      int idx = r * 256 + tid;
      int row = idx >> 2, ch = idx & 3;
      *(us8*)&Bs[row * 40 + ch * 8] =
          *(const us8*)&Bt[(size_t)(n0 + row) * 512 + k0 + ch * 8];
    }
    __syncthreads();
    short8 af[2], bf[4];
#pragma unroll
    for (int i = 0; i < 2; ++i)
      af[i] = *(const short8*)&As[(wr + i * 16 + colx) * 40 + quad * 8];
#pragma unroll
    for (int j = 0; j < 4; ++j)
      bf[j] = *(const short8*)&Bs[(wc + j * 16 + colx) * 40 + quad * 8];
#pragma unroll
    for (int i = 0; i < 2; ++i)
#pragma unroll
      for (int j = 0; j < 4; ++j)
        acc[i][j] = __builtin_amdgcn_mfma_f32_16x16x32_bf16(af[i], bf[j], acc[i][j], 0, 0, 0);
  }

  const bool isV = (blockIdx.x >= 8);
#pragma unroll
  for (int j = 0; j < 4; ++j) {
    int c = n0 + wc + j * 16 + colx;
    float bq = bias[c];
    if (!isV) {
#pragma unroll
      for (int i = 0; i < 2; ++i)
#pragma unroll
        for (int r = 0; r < 4; ++r) {
          int row = m0 + wr + i * 16 + quad * 4 + r;
          qk[(size_t)row * 1024 + c] = f2b(acc[i][j][r] + bq);
        }
    } else {
      int d = c - 1024;
#pragma unroll
      for (int i = 0; i < 2; ++i) {
        us4 o;
#pragma unroll
        for (int r = 0; r < 4; ++r) o[r] = f2b(acc[i][j][r] + bq);
        *(us4*)&vtp[(size_t)d * 4096 + m0 + wr + quad * 8 + i * 4] = o;
      }
    }
  }
}

// ---------------- out GEMM (64x64 tile) ----------------

__global__ __launch_bounds__(256) void k_gemm_out(const u16* __restrict__ A,
                                                  const u16* __restrict__ Bt,
                                                  const float* __restrict__ bias,
                                                  float* __restrict__ Cout) {
  __shared__ u16 As[64 * 40];
  __shared__ u16 Bs[64 * 40];
  const int tid = threadIdx.x;
  const int lane = tid & 63, wave = tid >> 6;
  const int colx = lane & 15, quad = lane >> 4;
  const int m0 = blockIdx.y * 64, n0 = blockIdx.x * 64;
  const int wr = (wave >> 1) * 32, wc = (wave & 1) * 32;
  const floatx4 fz = {0.f, 0.f, 0.f, 0.f};
  floatx4 acc[2][2];
#pragma unroll
  for (int i = 0; i < 2; ++i)
#pragma unroll
    for (int j = 0; j < 2; ++j) acc[i][j] = fz;

  for (int k0 = 0; k0 < 512; k0 += 32) {
    __syncthreads();
    {
      int row = tid >> 2, ch = tid & 3;
      *(us8*)&As[row * 40 + ch * 8] =
          *(const us8*)&A[(size_t)(m0 + row) * 512 + k0 + ch * 8];
      *(us8*)&Bs[row * 40 + ch * 8] =
          *(const us8*)&Bt[(size_t)(n0 + row) * 512 + k0 + ch * 8];
    }
    __syncthreads();
    short8 af[2], bf[2];
#pragma unroll
    for (int i = 0; i < 2; ++i)
      af[i] = *(const short8*)&As[(wr + i * 16 + colx) * 40 + quad * 8];
#pragma unroll
    for (int j = 0; j < 2; ++j)
      bf[j] = *(const short8*)&Bs[(wc + j * 16 + colx) * 40 + quad * 8];
#pragma unroll
    for (int i = 0; i < 2; ++i)
#pragma unroll
      for (int j = 0; j < 2; ++j)
        acc[i][j] = __builtin_amdgcn_mfma_f32_16x16x32_bf16(af[i], bf[j], acc[i][j], 0, 0, 0);
  }
#pragma unroll
  for (int j = 0; j < 2; ++j) {
    int c = n0 + wc + j * 16 + colx;
    float bq = bias[c];
#pragma unroll
    for (int i = 0; i < 2; ++i)
#pragma unroll
      for (int r = 0; r < 4; ++r) {
        int row = m0 + wr + i * 16 + quad * 4 + r;
        Cout[(size_t)row * 512 + c] = acc[i][j][r] + bq;
      }
  }
}

// ---------------- flash attention (fixed-max, linear, all-K=32) ----------------
// Q tile 64, KV tile 128, 512 threads = 8 waves: ih = wave&1 (q rows ih*32+),
// jq = wave>>1 (kv rows jq*32+). Q-frags in registers. P^T stays in registers
// as a K=32 A-frag under the pi-permutation baked into vtp's column order.
// l accumulated as per-lane fp32 (q = colx), shuffled to C-layout at the end.

__global__ __launch_bounds__(512, 4) void k_flash(const u16* __restrict__ qk,
                                                  const u16* __restrict__ vt,
                                                  const float* __restrict__ peT,
                                                  u16* __restrict__ ao) {
  __shared__ __align__(16) u16 smem[18176];  // 36352 B
  u16* Ks = smem;                            // [128][72]
  u16* Vts = smem + 9216;                    // [64][136]
  float* pes = (float*)(smem + 17920);       // [128]
  float* bufs = (float*)smem;                // epilogue overlay: 4 x 32x65 f32
  u16* fin = smem;                           // epilogue overlay: 64x68 u16

  const int tid = threadIdx.x;
  const int lane = tid & 63, wave = tid >> 6;
  const int colx = lane & 15, quad = lane >> 4;
  const int ih = wave & 1, jq = wave >> 1;
  const int q0 = blockIdx.x * 64;
  const int h = blockIdx.y;
  const float sscale = 0.125f * 1.4426950408889634f;
  const floatx4 fz = {0.f, 0.f, 0.f, 0.f};

  // prologue: stage Q through Ks region, pull loop-invariant Q-frags to regs
  {
    int row = tid >> 3, ch = tid & 7;
    *(us8*)&Ks[row * 72 + ch * 8] =
        *(const us8*)&qk[(size_t)(q0 + row) * 1024 + h * 64 + ch * 8];
  }
  __syncthreads();
  short8 qf[2][2];
#pragma unroll
  for (int i2 = 0; i2 < 2; ++i2)
#pragma unroll
    for (int kk = 0; kk < 2; ++kk)
      qf[i2][kk] = *(const short8*)&Ks[(ih * 32 + i2 * 16 + colx) * 72 + kk * 32 + quad * 8];

  floatx4 oacc[2][4];
  float rsum[2] = {0.0f, 0.0f};
#pragma unroll
  for (int i2 = 0; i2 < 2; ++i2)
#pragma unroll
    for (int cb = 0; cb < 4; ++cb) oacc[i2][cb] = fz;

  for (int j0 = 0; j0 < 4096; j0 += 128) {
    __syncthreads();
#pragma unroll
    for (int r = 0; r < 2; ++r) {   // K tile [128][64]
      int idx = r * 512 + tid;
      int row = idx >> 3, ch = idx & 7;
      *(us8*)&Ks[row * 72 + ch * 8] =
          *(const us8*)&qk[(size_t)(j0 + row) * 1024 + 512 + h * 64 + ch * 8];
    }
#pragma unroll
    for (int r = 0; r < 2; ++r) {   // V^T tile [64][128] (pi-permuted cols)
      int idx = r * 512 + tid;
      int row = idx >> 4, ch = idx & 15;
      *(us8*)&Vts[row * 136 + ch * 8] =
          *(const us8*)&vt[(size_t)(h * 64 + row) * 4096 + j0 + ch * 8];
    }
    if (tid < 128) pes[tid] = peT[h * 4096 + j0 + tid];
    __syncthreads();

    short8 kf[2][2];
#pragma unroll
    for (int j2 = 0; j2 < 2; ++j2)
#pragma unroll
      for (int kk = 0; kk < 2; ++kk)
        kf[j2][kk] = *(const short8*)&Ks[(jq * 32 + j2 * 16 + colx) * 72 + kk * 32 + quad * 8];
    short8 vf[4];
#pragma unroll
    for (int cb = 0; cb < 4; ++cb)
      vf[cb] = *(const short8*)&Vts[(cb * 16 + colx) * 136 + jq * 32 + quad * 8];
    floatx4 pev[2];
#pragma unroll
    for (int j2 = 0; j2 < 2; ++j2)
      pev[j2] = *(const floatx4*)&pes[jq * 32 + j2 * 16 + quad * 4];

#pragma unroll
    for (int i2 = 0; i2 < 2; ++i2) {
      floatx4 sacc[2] = {fz, fz};
#pragma unroll
      for (int j2 = 0; j2 < 2; ++j2)
#pragma unroll
        for (int kk = 0; kk < 2; ++kk)
          sacc[j2] = __builtin_amdgcn_mfma_f32_16x16x32_bf16(kf[j2][kk], qf[i2][kk], sacc[j2], 0, 0, 0);
      union { uint32_t w[4]; short8 s; } pk;
#pragma unroll
      for (int j2 = 0; j2 < 2; ++j2) {
        float p0 = fexp2(fmaf(sacc[j2][0], sscale, pev[j2][0]));
        float p1 = fexp2(fmaf(sacc[j2][1], sscale, pev[j2][1]));
        float p2 = fexp2(fmaf(sacc[j2][2], sscale, pev[j2][2]));
        float p3 = fexp2(fmaf(sacc[j2][3], sscale, pev[j2][3]));
        rsum[i2] += (p0 + p1) + (p2 + p3);
        pk.w[j2 * 2 + 0] = pkbf16(p0, p1);
        pk.w[j2 * 2 + 1] = pkbf16(p2, p3);
      }
#pragma unroll
      for (int cb = 0; cb < 4; ++cb)
        oacc[i2][cb] = __builtin_amdgcn_mfma_f32_16x16x32_bf16(pk.s, vf[cb], oacc[i2][cb], 0, 0, 0);
    }
  }

  // l: sum over quads (full 32-kv partial per q=colx), then to C-layout rows
  floatx4 lacc[2];
#pragma unroll
  for (int i2 = 0; i2 < 2; ++i2) {
    rsum[i2] += __shfl_xor(rsum[i2], 16);
    rsum[i2] += __shfl_xor(rsum[i2], 32);
#pragma unroll
    for (int r = 0; r < 4; ++r) lacc[i2][r] = __shfl(rsum[i2], quad * 4 + r, 16);
  }

  // ---- cross-wave reduction over jq (plain sums: fixed max) ----
  __syncthreads();  // Ks/Vts dead; bufs live
  float* s0 = bufs + (0 * 2 + ih) * 2080;
  float* s1 = bufs + (1 * 2 + ih) * 2080;
  if (jq >= 2) {     // S1: jq==2 -> slot k0, jq==3 -> slot k1
    float* b = (jq == 2) ? s0 : s1;
#pragma unroll
    for (int i2 = 0; i2 < 2; ++i2) {
#pragma unroll
      for (int cb = 0; cb < 4; ++cb)
#pragma unroll
        for (int r = 0; r < 4; ++r)
          b[(i2 * 16 + quad * 4 + r) * 65 + cb * 16 + colx] = oacc[i2][cb][r];
      if (colx == 0)
#pragma unroll
        for (int r = 0; r < 4; ++r)
          b[(i2 * 16 + quad * 4 + r) * 65 + 64] = lacc[i2][r];
    }
  }
  __syncthreads();
  if (jq < 2) {      // S2: jq==0 += slot k0, jq==1 += slot k1
    float* b = (jq == 0) ? s0 : s1;
#pragma unroll
    for (int i2 = 0; i2 < 2; ++i2) {
#pragma unroll
      for (int cb = 0; cb < 4; ++cb)
#pragma unroll
        for (int r = 0; r < 4; ++r)
          oacc[i2][cb][r] += b[(i2 * 16 + quad * 4 + r) * 65 + cb * 16 + colx];
#pragma unroll
      for (int r = 0; r < 4; ++r)
        lacc[i2][r] += b[(i2 * 16 + quad * 4 + r) * 65 + 64];  // LDS broadcast
    }
  }
  __syncthreads();
  if (jq == 1) {     // S3: write partial sum into slot k1
#pragma unroll
    for (int i2 = 0; i2 < 2; ++i2) {
#pragma unroll
      for (int cb = 0; cb < 4; ++cb)
#pragma unroll
        for (int r = 0; r < 4; ++r)
          s1[(i2 * 16 + quad * 4 + r) * 65 + cb * 16 + colx] = oacc[i2][cb][r];
      if (colx == 0)
#pragma unroll
        for (int r = 0; r < 4; ++r)
          s1[(i2 * 16 + quad * 4 + r) * 65 + 64] = lacc[i2][r];
    }
  }
  __syncthreads();
  if (jq == 0) {     // S4: full O,l; normalize; bf16 into fin (stride 68)
#pragma unroll
    for (int i2 = 0; i2 < 2; ++i2) {
#pragma unroll
      for (int cb = 0; cb < 4; ++cb)
#pragma unroll
        for (int r = 0; r < 4; ++r)
          oacc[i2][cb][r] += s1[(i2 * 16 + quad * 4 + r) * 65 + cb * 16 + colx];
#pragma unroll
      for (int r = 0; r < 4; ++r)
        lacc[i2][r] += s1[(i2 * 16 + quad * 4 + r) * 65 + 64];
#pragma unroll
      for (int r = 0; r < 4; ++r) {
        float inv = 1.0f / lacc[i2][r];
#pragma unroll
        for (int cb = 0; cb < 4; ++cb)
          fin[(ih * 32 + i2 * 16 + quad * 4 + r) * 68 + cb * 16 + colx] =
              f2b(oacc[i2][cb][r] * inv);
      }
    }
  }
  __syncthreads();
  // coalesced store of the 64x64 bf16 tile
  {
    int row = tid >> 3, ch = tid & 7;
    *(us8*)&ao[(size_t)(q0 + row) * 512 + h * 64 + ch * 8] =
        *(const us8*)&fin[row * 68 + ch * 8];
  }
}

// ---------------- launch ----------------

extern "C" void kernel_launch(void* const* d_in, const int* in_sizes, int n_in,
                              void* d_out, int out_size, void* d_ws, size_t ws_size,
                              hipStream_t stream) {
  const float* x     = (const float*)d_in[0];
  const float* pe    = (const float*)d_in[1];
  const float* w_qkv = (const float*)d_in[2];
  const float* b_qkv = (const float*)d_in[3];
  const float* w_pe  = (const float*)d_in[4];
  const float* b_pe  = (const float*)d_in[5];
  const float* w_out = (const float*)d_in[6];
  const float* b_out = (const float*)d_in[7];
  float* out = (float*)d_out;

  // workspace layout (u16 elements)
  u16* xb    = (u16*)d_ws;              // 4096*512
  u16* wqkvT = xb    + 2097152;         // 1536*512
  u16* woutT = wqkvT + 786432;          // 512*512
  u16* qk    = woutT + 262144;          // 4096*1024 (Q|K)
  u16* vt    = qk    + 4194304;         // 512*4096 (pi-permuted V^T)
  u16* ao    = vt    + 2097152;         // 4096*512
  float* peT = (float*)(ao + 2097152);  // 8*4096 floats

  k_prep<<<3200, 256, 0, stream>>>(x, xb, w_qkv, wqkvT, w_out, woutT,
                                   pe, w_pe, b_pe, peT);
  k_gemm_qkv<<<dim3(12, 64), 256, 0, stream>>>(xb, wqkvT, b_qkv, qk, vt);
  k_flash<<<dim3(64, 8), 512, 0, stream>>>(qk, vt, peT, ao);
  k_gemm_out<<<dim3(8, 64), 256, 0, stream>>>(ao, woutT, b_out, out);
}

// Round 6
// 149.190 us; speedup vs baseline: 1.5833x; 1.0443x over previous
//
#include <hip/hip_runtime.h>
#include <stdint.h>
#include <stddef.h>

// GRIT attention, MI355X bf16-MFMA implementation, round 6.
// softmax_j(q.k*scale + pe[j] - pe[i]) == softmax_j(q.k*scale + pe[j])
// -> flash attention with per-column bias; fixed-max (M=16, exp2 domain) makes
//    the KV loop linear (R4); PV is K=32 MFMA via pi-permuted vt (R5).
// R6: global_load_lds(16B) staging + XOR-swizzled unpadded LDS (2-way-only
//     bank aliasing = free) + true double-buffer, ONE barrier per K-iter:
//     prefetch(next) -> compute(cur) -> barrier, so the vmcnt(0) drain at the
//     barrier covers loads issued a full compute-phase earlier.

typedef unsigned short u16;
typedef __attribute__((ext_vector_type(8))) short short8;      // K=32 MFMA A/B frag
typedef __attribute__((ext_vector_type(8))) unsigned short us8;
typedef __attribute__((ext_vector_type(4))) unsigned short us4;
typedef __attribute__((ext_vector_type(4))) float floatx4;

__device__ __forceinline__ u16 f2b(float f) {
  union { float f; uint32_t u; } v; v.f = f;
  uint32_t u = v.u;
  return (u16)((u + 0x7fffu + ((u >> 16) & 1u)) >> 16);  // RNE
}

// pack two f32 -> two bf16 (round-half-up) in one dword: add, add, v_perm
__device__ __forceinline__ uint32_t pkbf16(float a, float b) {
  union { float f; uint32_t u; } x, y; x.f = a; y.f = b;
  return __builtin_amdgcn_perm(y.u + 0x8000u, x.u + 0x8000u, 0x07060302u);
}

#if __has_builtin(__builtin_amdgcn_exp2f)
__device__ __forceinline__ float fexp2(float x) { return __builtin_amdgcn_exp2f(x); }
#else
__device__ __forceinline__ float fexp2(float x) { return exp2f(x); }
#endif

// async 16B/lane global->LDS; LDS dest is wave-uniform base + lane*16
__device__ __forceinline__ void gld16(const u16* g, u16* l) {
  __builtin_amdgcn_global_load_lds(
      (const __attribute__((address_space(1))) uint32_t*)(const void*)g,
      (__attribute__((address_space(3))) uint32_t*)(void*)l, 16, 0, 0);
}

// ---------------- fused prep ----------------

__device__ __forceinline__ void tr_tile(const float* __restrict__ in,
                                        u16* __restrict__ out, int R, int C,
                                        int bx, int by, u16 (*tile)[33]) {
  int tx = threadIdx.x & 31, ty = threadIdx.x >> 5;
  int c0 = bx * 32, r0 = by * 32;
#pragma unroll
  for (int i = 0; i < 32; i += 8)
    tile[ty + i][tx] = f2b(in[(size_t)(r0 + ty + i) * C + c0 + tx]);
  __syncthreads();
#pragma unroll
  for (int i = 0; i < 32; i += 8)
    out[(size_t)(c0 + ty + i) * R + r0 + tx] = tile[tx][ty + i];
}

__global__ __launch_bounds__(256) void k_prep(
    const float* __restrict__ x, u16* __restrict__ xb,
    const float* __restrict__ w_qkv, u16* __restrict__ wqkvT,
    const float* __restrict__ w_out, u16* __restrict__ woutT,
    const float* __restrict__ pe, const float* __restrict__ w_pe,
    const float* __restrict__ b_pe, float* __restrict__ peT) {
  __shared__ u16 tile[32][33];
  int b = blockIdx.x;
  if (b < 2048) {
    int i = b * 256 + threadIdx.x;
    float4 v = ((const float4*)x)[i];
    uint2 o = make_uint2(pkbf16(v.x, v.y), pkbf16(v.z, v.w));
    ((uint2*)xb)[i] = o;
  } else if (b < 2816) {
    int idx = b - 2048;
    tr_tile(w_qkv, wqkvT, 512, 1536, idx % 48, idx / 48, tile);
  } else if (b < 3072) {
    int idx = b - 2816;
    tr_tile(w_out, woutT, 512, 512, idx % 16, idx / 16, tile);
  } else {
    int idx = (b - 3072) * 256 + threadIdx.x;
    int h = idx >> 12, n = idx & 4095;
    float acc = b_pe[h];
#pragma unroll
    for (int d = 0; d < 16; ++d) acc = fmaf(pe[n * 16 + d], w_pe[d * 8 + h], acc);
    peT[h * 4096 + n] = acc * 1.4426950408889634f - 16.0f;
  }
}

// ---------------- QKV GEMM (64x128 tile, BK=32, async dbuf) ----------------
// LDS rows = 32 u16 (4 chunks of 16B), slot = chunk ^ ((row>>1)&3).
// cols < 1024 (Q|K) -> qk[n][1024]; cols >= 1024 (V) -> vtp[d][4096] transposed
// with pi: value for n = 32a+16b+4q+r stored at 32a+8q+4b+r.

__global__ __launch_bounds__(256) void k_gemm_qkv(const u16* __restrict__ A,
                                                  const u16* __restrict__ Bt,
                                                  const float* __restrict__ bias,
                                                  u16* __restrict__ qk,
                                                  u16* __restrict__ vtp) {
  __shared__ __align__(16) u16 smem[12288];  // As:2x2048 @0, Bs:2x4096 @4096
  const int tid = threadIdx.x;
  const int lane = tid & 63, wave = tid >> 6;
  const int colx = lane & 15, quad = lane >> 4;
  const int m0 = blockIdx.y * 64, n0 = blockIdx.x * 128;
  const int wr = (wave >> 1) * 32, wc = (wave & 1) * 64;
  const int scA = (lane & 3) ^ ((lane >> 3) & 3);  // staging source chunk
  const int sx = (colx >> 1) & 3;                  // frag-read slot xor
  const floatx4 fz = {0.f, 0.f, 0.f, 0.f};
  floatx4 acc[2][4];
#pragma unroll
  for (int i = 0; i < 2; ++i)
#pragma unroll
    for (int j = 0; j < 4; ++j) acc[i][j] = fz;

#define PREF_QKV(k0, b)                                                       \
  {                                                                           \
    int rowa = wave * 16 + (lane >> 2);                                       \
    gld16(&A[(size_t)(m0 + rowa) * 512 + (k0) + scA * 8],                     \
          &smem[(b) * 2048 + wave * 512 + lane * 8]);                         \
    _Pragma("unroll") for (int c = 0; c < 2; ++c) {                           \
      int rowb = wave * 32 + c * 16 + (lane >> 2);                            \
      gld16(&Bt[(size_t)(n0 + rowb) * 512 + (k0) + scA * 8],                  \
            &smem[4096 + (b) * 4096 + wave * 1024 + c * 512 + lane * 8]);     \
    }                                                                         \
  }

  PREF_QKV(0, 0);
  __syncthreads();
  for (int it = 0; it < 16; ++it) {
    int cur = it & 1;
    if (it < 15) PREF_QKV((it + 1) * 32, cur ^ 1);
    const u16* As = &smem[cur * 2048];
    const u16* Bs = &smem[4096 + cur * 4096];
    short8 af[2], bf[4];
#pragma unroll
    for (int i = 0; i < 2; ++i)
      af[i] = *(const short8*)&As[(wr + i * 16 + colx) * 32 + (quad ^ sx) * 8];
#pragma unroll
    for (int j = 0; j < 4; ++j)
      bf[j] = *(const short8*)&Bs[(wc + j * 16 + colx) * 32 + (quad ^ sx) * 8];
#pragma unroll
    for (int i = 0; i < 2; ++i)
#pragma unroll
      for (int j = 0; j < 4; ++j)
        acc[i][j] = __builtin_amdgcn_mfma_f32_16x16x32_bf16(af[i], bf[j], acc[i][j], 0, 0, 0);
    __syncthreads();
  }

  const bool isV = (blockIdx.x >= 8);
#pragma unroll
  for (int j = 0; j < 4; ++j) {
    int c = n0 + wc + j * 16 + colx;
    float bq = bias[c];
    if (!isV) {
#pragma unroll
      for (int i = 0; i < 2; ++i)
#pragma unroll
        for (int r = 0; r < 4; ++r) {
          int row = m0 + wr + i * 16 + quad * 4 + r;
          qk[(size_t)row * 1024 + c] = f2b(acc[i][j][r] + bq);
        }
    } else {
      int d = c - 1024;
#pragma unroll
      for (int i = 0; i < 2; ++i) {
        us4 o;
#pragma unroll
        for (int r = 0; r < 4; ++r) o[r] = f2b(acc[i][j][r] + bq);
        *(us4*)&vtp[(size_t)d * 4096 + m0 + wr + quad * 8 + i * 4] = o;
      }
    }
  }
#undef PREF_QKV
}

// ---------------- out GEMM (64x64 tile, BK=32, async dbuf) ----------------

__global__ __launch_bounds__(256) void k_gemm_out(const u16* __restrict__ A,
                                                  const u16* __restrict__ Bt,
                                                  const float* __restrict__ bias,
                                                  float* __restrict__ Cout) {
  __shared__ __align__(16) u16 smem[8192];  // As:2x2048 @0, Bs:2x2048 @4096
  const int tid = threadIdx.x;
  const int lane = tid & 63, wave = tid >> 6;
  const int colx = lane & 15, quad = lane >> 4;
  const int m0 = blockIdx.y * 64, n0 = blockIdx.x * 64;
  const int wr = (wave >> 1) * 32, wc = (wave & 1) * 32;
  const int scA = (lane & 3) ^ ((lane >> 3) & 3);
  const int sx = (colx >> 1) & 3;
  const floatx4 fz = {0.f, 0.f, 0.f, 0.f};
  floatx4 acc[2][2];
#pragma unroll
  for (int i = 0; i < 2; ++i)
#pragma unroll
    for (int j = 0; j < 2; ++j) acc[i][j] = fz;

#define PREF_OUT(k0, b)                                                       \
  {                                                                           \
    int rowa = wave * 16 + (lane >> 2);                                       \
    gld16(&A[(size_t)(m0 + rowa) * 512 + (k0) + scA * 8],                     \
          &smem[(b) * 2048 + wave * 512 + lane * 8]);                         \
    gld16(&Bt[(size_t)(n0 + rowa) * 512 + (k0) + scA * 8],                    \
          &smem[4096 + (b) * 2048 + wave * 512 + lane * 8]);                  \
  }

  PREF_OUT(0, 0);
  __syncthreads();
  for (int it = 0; it < 16; ++it) {
    int cur = it & 1;
    if (it < 15) PREF_OUT((it + 1) * 32, cur ^ 1);
    const u16* As = &smem[cur * 2048];
    const u16* Bs = &smem[4096 + cur * 2048];
    short8 af[2], bf[2];
#pragma unroll
    for (int i = 0; i < 2; ++i)
      af[i] = *(const short8*)&As[(wr + i * 16 + colx) * 32 + (quad ^ sx) * 8];
#pragma unroll
    for (int j = 0; j < 2; ++j)
      bf[j] = *(const short8*)&Bs[(wc + j * 16 + colx) * 32 + (quad ^ sx) * 8];
#pragma unroll
    for (int i = 0; i < 2; ++i)
#pragma unroll
      for (int j = 0; j < 2; ++j)
        acc[i][j] = __builtin_amdgcn_mfma_f32_16x16x32_bf16(af[i], bf[j], acc[i][j], 0, 0, 0);
    __syncthreads();
  }
#pragma unroll
  for (int j = 0; j < 2; ++j) {
    int c = n0 + wc + j * 16 + colx;
    float bq = bias[c];
#pragma unroll
    for (int i = 0; i < 2; ++i)
#pragma unroll
      for (int r = 0; r < 4; ++r) {
        int row = m0 + wr + i * 16 + quad * 4 + r;
        Cout[(size_t)row * 512 + c] = acc[i][j][r] + bq;
      }
  }
#undef PREF_OUT
}

// ---------------- flash attention (fixed-max, linear, all-K=32, async dbuf) --
// Q tile 64, KV tile 128, 512 threads = 8 waves: ih = wave&1, jq = wave>>1.
// LDS (u16 idx): Qs@0 [64][64] slot^=(row&7-style); K bufs @4096+b*8192
// [128 rows][64] slot=chunk^(row&7); V bufs @20480+b*8192 [64 rows][128]
// slot=chunk^(row&15); pes @36864+b*256 (f32[128]).

__global__ __launch_bounds__(512, 4) void k_flash(const u16* __restrict__ qk,
                                                  const u16* __restrict__ vt,
                                                  const float* __restrict__ peT,
                                                  u16* __restrict__ ao) {
  __shared__ __align__(16) u16 smem[37376];
  float* bufs = (float*)smem;   // epilogue overlay: 4 x 32x65 f32 (33280 B)
  u16* fin = smem;              // epilogue overlay: 64x68 u16

  const int tid = threadIdx.x;
  const int lane = tid & 63, wave = tid >> 6;
  const int colx = lane & 15, quad = lane >> 4;
  const int ih = wave & 1, jq = wave >> 1;
  const int q0 = blockIdx.x * 64;
  const int h = blockIdx.y;
  const float sscale = 0.125f * 1.4426950408889634f;
  const floatx4 fz = {0.f, 0.f, 0.f, 0.f};

  const int scK = (lane & 7) ^ (lane >> 3);            // K staging src chunk
  const int rV = wave * 8 + (lane >> 4);               // V staging row (c=0)
  const int scV0 = (lane & 15) ^ (rV & 15);
  const int scV1 = (lane & 15) ^ ((rV + 4) & 15);

#define PREF_F(j0n, b)                                                        \
  {                                                                           \
    _Pragma("unroll") for (int c = 0; c < 2; ++c) {                           \
      int row = wave * 16 + c * 8 + (lane >> 3);                              \
      gld16(&qk[(size_t)((j0n) + row) * 1024 + 512 + h * 64 + scK * 8],       \
            &smem[4096 + (b) * 8192 + wave * 1024 + c * 512 + lane * 8]);     \
    }                                                                         \
    gld16(&vt[(size_t)(h * 64 + rV) * 4096 + (j0n) + scV0 * 8],               \
          &smem[20480 + (b) * 8192 + wave * 1024 + lane * 8]);                \
    gld16(&vt[(size_t)(h * 64 + rV + 4) * 4096 + (j0n) + scV1 * 8],           \
          &smem[20480 + (b) * 8192 + wave * 1024 + 512 + lane * 8]);          \
    if (tid < 128)                                                            \
      ((float*)(smem + 36864 + (b) * 256))[tid] = peT[h * 4096 + (j0n) + tid];\
  }

  // prologue: stage Q (swizzled ds_write) + prefetch tile 0
  {
    int row = tid >> 3, ch = tid & 7;
    int slot = ch ^ (row & 7);
    *(us8*)&smem[row * 64 + slot * 8] =
        *(const us8*)&qk[(size_t)(q0 + row) * 1024 + h * 64 + ch * 8];
  }
  PREF_F(0, 0);
  __syncthreads();

  short8 qf[2][2];
#pragma unroll
  for (int i2 = 0; i2 < 2; ++i2)
#pragma unroll
    for (int kk = 0; kk < 2; ++kk) {
      int row = ih * 32 + i2 * 16 + colx;
      qf[i2][kk] = *(const short8*)&smem[row * 64 + ((kk * 4 + quad) ^ (colx & 7)) * 8];
    }

  floatx4 oacc[2][4];
  float rsum[2] = {0.0f, 0.0f};
#pragma unroll
  for (int i2 = 0; i2 < 2; ++i2)
#pragma unroll
    for (int cb = 0; cb < 4; ++cb) oacc[i2][cb] = fz;

  for (int it = 0; it < 32; ++it) {
    const int cur = it & 1;
    if (it < 31) PREF_F((it + 1) * 128, cur ^ 1);

    const u16* Ks = &smem[4096 + cur * 8192];
    const u16* Vts = &smem[20480 + cur * 8192];
    const float* pes = (const float*)(smem + 36864 + cur * 256);

    short8 kf[2][2];
#pragma unroll
    for (int j2 = 0; j2 < 2; ++j2)
#pragma unroll
      for (int kk = 0; kk < 2; ++kk) {
        int row = jq * 32 + j2 * 16 + colx;
        kf[j2][kk] = *(const short8*)&Ks[row * 64 + ((kk * 4 + quad) ^ (colx & 7)) * 8];
      }
    short8 vf[4];
#pragma unroll
    for (int cb = 0; cb < 4; ++cb) {
      int row = cb * 16 + colx;
      vf[cb] = *(const short8*)&Vts[row * 128 + ((jq * 4 + quad) ^ colx) * 8];
    }
    floatx4 pev[2];
#pragma unroll
    for (int j2 = 0; j2 < 2; ++j2)
      pev[j2] = *(const floatx4*)&pes[jq * 32 + j2 * 16 + quad * 4];

#pragma unroll
    for (int i2 = 0; i2 < 2; ++i2) {
      floatx4 sacc[2] = {fz, fz};
#pragma unroll
      for (int j2 = 0; j2 < 2; ++j2)
#pragma unroll
        for (int kk = 0; kk < 2; ++kk)
          sacc[j2] = __builtin_amdgcn_mfma_f32_16x16x32_bf16(kf[j2][kk], qf[i2][kk], sacc[j2], 0, 0, 0);
      union { uint32_t w[4]; short8 s; } pk;
#pragma unroll
      for (int j2 = 0; j2 < 2; ++j2) {
        float p0 = fexp2(fmaf(sacc[j2][0], sscale, pev[j2][0]));
        float p1 = fexp2(fmaf(sacc[j2][1], sscale, pev[j2][1]));
        float p2 = fexp2(fmaf(sacc[j2][2], sscale, pev[j2][2]));
        float p3 = fexp2(fmaf(sacc[j2][3], sscale, pev[j2][3]));
        rsum[i2] += (p0 + p1) + (p2 + p3);
        pk.w[j2 * 2 + 0] = pkbf16(p0, p1);
        pk.w[j2 * 2 + 1] = pkbf16(p2, p3);
      }
#pragma unroll
      for (int cb = 0; cb < 4; ++cb)
        oacc[i2][cb] = __builtin_amdgcn_mfma_f32_16x16x32_bf16(pk.s, vf[cb], oacc[i2][cb], 0, 0, 0);
    }
    __syncthreads();
  }

  // l: sum over quads, then to C-layout rows
  floatx4 lacc[2];
#pragma unroll
  for (int i2 = 0; i2 < 2; ++i2) {
    rsum[i2] += __shfl_xor(rsum[i2], 16);
    rsum[i2] += __shfl_xor(rsum[i2], 32);
#pragma unroll
    for (int r = 0; r < 4; ++r) lacc[i2][r] = __shfl(rsum[i2], quad * 4 + r, 16);
  }

  // ---- cross-wave reduction over jq (plain sums: fixed max) ----
  float* s0 = bufs + (0 * 2 + ih) * 2080;
  float* s1 = bufs + (1 * 2 + ih) * 2080;
  if (jq >= 2) {     // S1
    float* b = (jq == 2) ? s0 : s1;
#pragma unroll
    for (int i2 = 0; i2 < 2; ++i2) {
#pragma unroll
      for (int cb = 0; cb < 4; ++cb)
#pragma unroll
        for (int r = 0; r < 4; ++r)
          b[(i2 * 16 + quad * 4 + r) * 65 + cb * 16 + colx] = oacc[i2][cb][r];
      if (colx == 0)
#pragma unroll
        for (int r = 0; r < 4; ++r)
          b[(i2 * 16 + quad * 4 + r) * 65 + 64] = lacc[i2][r];
    }
  }
  __syncthreads();
  if (jq < 2) {      // S2
    float* b = (jq == 0) ? s0 : s1;
#pragma unroll
    for (int i2 = 0; i2 < 2; ++i2) {
#pragma unroll
      for (int cb = 0; cb < 4; ++cb)
#pragma unroll
        for (int r = 0; r < 4; ++r)
          oacc[i2][cb][r] += b[(i2 * 16 + quad * 4 + r) * 65 + cb * 16 + colx];
#pragma unroll
      for (int r = 0; r < 4; ++r)
        lacc[i2][r] += b[(i2 * 16 + quad * 4 + r) * 65 + 64];
    }
  }
  __syncthreads();
  if (jq == 1) {     // S3
#pragma unroll
    for (int i2 = 0; i2 < 2; ++i2) {
#pragma unroll
      for (int cb = 0; cb < 4; ++cb)
#pragma unroll
        for (int r = 0; r < 4; ++r)
          s1[(i2 * 16 + quad * 4 + r) * 65 + cb * 16 + colx] = oacc[i2][cb][r];
      if (colx == 0)
#pragma unroll
        for (int r = 0; r < 4; ++r)
          s1[(i2 * 16 + quad * 4 + r) * 65 + 64] = lacc[i2][r];
    }
  }
  __syncthreads();
  if (jq == 0) {     // S4: normalize; bf16 into fin (stride 68)
#pragma unroll
    for (int i2 = 0; i2 < 2; ++i2) {
#pragma unroll
      for (int cb = 0; cb < 4; ++cb)
#pragma unroll
        for (int r = 0; r < 4; ++r)
          oacc[i2][cb][r] += s1[(i2 * 16 + quad * 4 + r) * 65 + cb * 16 + colx];
#pragma unroll
      for (int r = 0; r < 4; ++r)
        lacc[i2][r] += s1[(i2 * 16 + quad * 4 + r) * 65 + 64];
#pragma unroll
      for (int r = 0; r < 4; ++r) {
        float inv = 1.0f / lacc[i2][r];
#pragma unroll
        for (int cb = 0; cb < 4; ++cb)
          fin[(ih * 32 + i2 * 16 + quad * 4 + r) * 68 + cb * 16 + colx] =
              f2b(oacc[i2][cb][r] * inv);
      }
    }
  }
  __syncthreads();
  {
    int row = tid >> 3, ch = tid & 7;
    *(us8*)&ao[(size_t)(q0 + row) * 512 + h * 64 + ch * 8] =
        *(const us8*)&fin[row * 68 + ch * 8];
  }
#undef PREF_F
}

// ---------------- launch ----------------

extern "C" void kernel_launch(void* const* d_in, const int* in_sizes, int n_in,
                              void* d_out, int out_size, void* d_ws, size_t ws_size,
                              hipStream_t stream) {
  const float* x     = (const float*)d_in[0];
  const float* pe    = (const float*)d_in[1];
  const float* w_qkv = (const float*)d_in[2];
  const float* b_qkv = (const float*)d_in[3];
  const float* w_pe  = (const float*)d_in[4];
  const float* b_pe  = (const float*)d_in[5];
  const float* w_out = (const float*)d_in[6];
  const float* b_out = (const float*)d_in[7];
  float* out = (float*)d_out;

  // workspace layout (u16 elements)
  u16* xb    = (u16*)d_ws;              // 4096*512
  u16* wqkvT = xb    + 2097152;         // 1536*512
  u16* woutT = wqkvT + 786432;          // 512*512
  u16* qk    = woutT + 262144;          // 4096*1024 (Q|K)
  u16* vt    = qk    + 4194304;         // 512*4096 (pi-permuted V^T)
  u16* ao    = vt    + 2097152;         // 4096*512
  float* peT = (float*)(ao + 2097152);  // 8*4096 floats

  k_prep<<<3200, 256, 0, stream>>>(x, xb, w_qkv, wqkvT, w_out, woutT,
                                   pe, w_pe, b_pe, peT);
  k_gemm_qkv<<<dim3(12, 64), 256, 0, stream>>>(xb, wqkvT, b_qkv, qk, vt);
  k_flash<<<dim3(64, 8), 512, 0, stream>>>(qk, vt, peT, ao);
  k_gemm_out<<<dim3(8, 64), 256, 0, stream>>>(ao, woutT, b_out, out);
}